// Round 4
// baseline (1809.384 us; speedup 1.0000x reference)
//
#include <hip/hip_runtime.h>

typedef unsigned short u16;
typedef __attribute__((ext_vector_type(4))) float f32x4;
typedef __attribute__((ext_vector_type(8))) short s16x8;

#define NND 50000      // nodes per side (NU == NI)
#define EDG 1600000    // edges per relation
#define NBK 391        // buckets per relation = ceil(NND/128)
#define TOTB (3 * NBK)
#define TS 4096        // edges per scatter tile
#define SCAP 8192      // kb_build sort capacity (mean 4092, sd ~64 -> never exceeded)

__device__ __forceinline__ u16 f2b(float f) {
  union { float f; unsigned u; } c; c.f = f;
  unsigned r = c.u + 0x7fff + ((c.u >> 16) & 1);   // RNE
  return (u16)(r >> 16);
}
__device__ __forceinline__ float b2f(u16 b) {
  union { float f; unsigned u; } c; c.u = ((unsigned)b) << 16; return c.f;
}

// ---------------- zero int buffer ----------------
__global__ void k_zero(int* p, int n) {
  int i = blockIdx.x * 256 + threadIdx.x;
  if (i < n) p[i] = 0;
}

// ---------------- Wt[r][n][kk] = Wv[r][kk][n]  (bf16, 3*512*256) ----------------
__global__ void k_prepw(const float* __restrict__ Wv, u16* __restrict__ Wt) {
  int tid = blockIdx.x * 256 + threadIdx.x;
  if (tid < 3 * 512 * 256) {
    int r = tid / (512 * 256); int rem = tid - r * 512 * 256;
    int n = rem >> 8; int kk = rem & 255;
    Wt[tid] = f2b(Wv[((size_t)r * 256 + kk) * 512 + n]);
  }
}

// ---------------- fused q/k weights: FW[r][o][kk] = sum_j Wv[r][kk][j]*Wqk[r][j][o] ----------------
__global__ void k_fusew(const float* __restrict__ Wv, const float* __restrict__ bv,
                        const float* __restrict__ Wq, const float* __restrict__ bq,
                        const float* __restrict__ Wk, const float* __restrict__ bk,
                        float* __restrict__ FW, float* __restrict__ FB) {
  int tid = blockIdx.x * 256 + threadIdx.x;
  if (tid < 3 * 16 * 256) {
    int r = tid >> 12, o = (tid >> 8) & 15, kk = tid & 255;
    const float* wv = Wv + ((size_t)r * 256 + kk) * 512;
    const float* wqk = (o < 8) ? (Wq + r * 512 * 8 + o) : (Wk + r * 512 * 8 + (o - 8));
    float s = 0.f;
    for (int j = 0; j < 512; j++) s += wv[j] * wqk[j * 8];
    FW[tid] = s;
  }
  if (tid < 48) {
    int r = tid / 16, o = tid % 16;
    const float* wqk = (o < 8) ? (Wq + r * 512 * 8 + o) : (Wk + r * 512 * 8 + (o - 8));
    const float* bvp = bv + r * 512;
    float s = (o < 8) ? bq[r * 8 + o] : bk[r * 8 + (o - 8)];
    for (int j = 0; j < 512; j++) s += bvp[j] * wqk[j * 8];
    FB[tid] = s;
  }
}

// ================= bucket-partitioned CSR build =================
// bucket = dst >> 7 (128 nodes per bucket), per relation.

__global__ void kb_count(const int* __restrict__ d1, const int* __restrict__ d2,
                         const int* __restrict__ d3, int* __restrict__ BC) {
  __shared__ int h[NBK];
  int tid = threadIdx.x;
  int r = blockIdx.y;
  const int* d = (r == 0) ? d1 : (r == 1) ? d2 : d3;
  for (int b = tid; b < NBK; b += 256) h[b] = 0;
  __syncthreads();
  for (int e = blockIdx.x * 256 + tid; e < EDG; e += 256 * gridDim.x)
    atomicAdd(&h[d[e] >> 7], 1);
  __syncthreads();
  for (int b = tid; b < NBK; b += 256)
    if (h[b]) atomicAdd(&BC[r * NBK + b], h[b]);
}

__global__ void kb_scan(const int* __restrict__ BC, int* __restrict__ BB,
                        int* __restrict__ BCUR, int* __restrict__ rp) {
  __shared__ int a[2][2048];
  int t = threadIdx.x;   // 1024
  a[0][t]        = (t < TOTB) ? BC[t] : 0;
  a[0][t + 1024] = (t + 1024 < TOTB) ? BC[t + 1024] : 0;
  __syncthreads();
  int s = 0;
  for (int off = 1; off < 2048; off <<= 1) {
    int v0 = a[s][t];        if (t >= off) v0 += a[s][t - off];
    int v1 = a[s][t + 1024]; if (t + 1024 >= off) v1 += a[s][t + 1024 - off];
    __syncthreads();
    a[s ^ 1][t] = v0; a[s ^ 1][t + 1024] = v1;
    __syncthreads();
    s ^= 1;
  }
  if (t < TOTB)        { int e = a[s][t] - BC[t];               BB[t] = e;        BCUR[t] = e; }
  if (t + 1024 < TOTB) { int e = a[s][t + 1024] - BC[t + 1024]; BB[t + 1024] = e; BCUR[t + 1024] = e; }
  if (t == 0) rp[3 * NND] = 3 * EDG;
}

__global__ void __launch_bounds__(256) kb_scatter(
    const int* __restrict__ s1, const int* __restrict__ d1,
    const int* __restrict__ s2, const int* __restrict__ d2,
    const int* __restrict__ s3, const int* __restrict__ d3,
    int* __restrict__ BCUR, unsigned* __restrict__ pairs) {
  __shared__ int h[NBK];
  __shared__ int bbase[NBK];
  int tid = threadIdx.x;
  int r = blockIdx.y;
  const int* dp = (r == 0) ? d1 : (r == 1) ? d2 : d3;
  const int* sp = (r == 0) ? s1 : (r == 1) ? s2 : s3;
  int e0 = blockIdx.x * TS;
  int n = EDG - e0; if (n > TS) n = TS;
  for (int b = tid; b < NBK; b += 256) h[b] = 0;
  __syncthreads();
  int eb[16]; unsigned ev[16];
#pragma unroll
  for (int k = 0; k < 16; k++) {
    int i = k * 256 + tid;
    if (i < n) {
      int d = dp[e0 + i], ss = sp[e0 + i];
      eb[k] = d >> 7;
      ev[k] = ((unsigned)(d & 127) << 16) | (unsigned)ss;
      atomicAdd(&h[eb[k]], 1);
    } else eb[k] = -1;
  }
  __syncthreads();
  for (int b = tid; b < NBK; b += 256) {
    int c = h[b];
    bbase[b] = c ? atomicAdd(&BCUR[r * NBK + b], c) : 0;
  }
  __syncthreads();
  for (int b = tid; b < NBK; b += 256) h[b] = 0;   // reuse as local cursor
  __syncthreads();
#pragma unroll
  for (int k = 0; k < 16; k++) {
    if (eb[k] >= 0) {
      int off = atomicAdd(&h[eb[k]], 1);
      pairs[bbase[eb[k]] + off] = ev[k];
    }
  }
}

// -- per-bucket: bitonic-sort keys (dstLow<<16|src) -> csrc (src-sorted per dst) + rowptr --
__global__ void __launch_bounds__(256) kb_build(
    const unsigned* __restrict__ pairs, const int* __restrict__ BB,
    const int* __restrict__ BC, int* __restrict__ rp, int* __restrict__ csrc) {
  __shared__ unsigned A[SCAP];
  int t = threadIdx.x;
  int r = blockIdx.y, bx = blockIdx.x;
  int bin = r * NBK + bx;
  int base = BB[bin], cnt = BC[bin];
  int node0 = bx << 7;
  int nloc = NND - node0; if (nloc > 128) nloc = 128;

  if (cnt > SCAP) {   // statistically impossible fallback: unsorted grouping
    int* cntl = (int*)A; int* sc = (int*)A + 128; int* curl = (int*)A + 256;
    if (t < 128) cntl[t] = 0;
    __syncthreads();
    for (int i = t; i < cnt; i += 256) atomicAdd(&cntl[pairs[base + i] >> 16], 1);
    __syncthreads();
    if (t < 128) sc[t] = cntl[t];
    __syncthreads();
    for (int off = 1; off < 128; off <<= 1) {
      int v = 0;
      if (t < 128) { v = sc[t]; if (t >= off) v += sc[t - off]; }
      __syncthreads();
      if (t < 128) sc[t] = v;
      __syncthreads();
    }
    if (t < 128) {
      int excl = sc[t] - cntl[t];
      if (t < nloc) rp[r * NND + node0 + t] = base + excl;
      curl[t] = base + excl;
    }
    __syncthreads();
    for (int i = t; i < cnt; i += 256) {
      unsigned v = pairs[base + i];
      int p = atomicAdd(&curl[v >> 16], 1);
      csrc[p] = (int)(v & 0xFFFFu);
    }
    return;
  }

  int n = 1024; while (n < cnt) n <<= 1;            // pow2 sort size
  for (int i = t; i < n; i += 256) A[i] = (i < cnt) ? pairs[base + i] : 0xFFFFFFFFu;
  __syncthreads();
  for (int ksz = 2; ksz <= n; ksz <<= 1) {
    for (int j = ksz >> 1; j > 0; j >>= 1) {
      for (int i = t; i < n; i += 256) {
        int p = i ^ j;
        if (p > i) {
          unsigned a = A[i], b = A[p];
          bool up = ((i & ksz) == 0);
          if ((a > b) == up) { A[i] = b; A[p] = a; }
        }
      }
      __syncthreads();
    }
  }
  for (int i = t; i < cnt; i += 256) {
    unsigned key = A[i];
    int d = (int)(key >> 16);
    int dprev = (i == 0) ? -1 : (int)(A[i - 1] >> 16);
    for (int x = dprev + 1; x <= d; x++) rp[r * NND + node0 + x] = base + i;
    csrc[base + i] = (int)(key & 0xFFFFu);
  }
  int dlast = (cnt > 0) ? (int)(A[cnt - 1] >> 16) : -1;
  for (int x = dlast + 1 + t; x < nloc; x += 256) rp[r * NND + node0 + x] = base + cnt;
}

// ---------------- bf16 MFMA GEMM: H[M][f*8+h] = bf16(A_f32[M,256] @ Wv + bv)  (head-transposed) ----------------
__global__ void __launch_bounds__(256) k_gemm(const float* __restrict__ A, const u16* __restrict__ Bt,
                                              const float* __restrict__ bias, u16* __restrict__ C, int M) {
  __shared__ u16 sA[128 * 40];
  __shared__ u16 sB[128 * 40];
  int tid = threadIdx.x;
  int lane = tid & 63, wid = tid >> 6;
  int wm = wid >> 1, wn = wid & 1;
  int l15 = lane & 15, l4 = lane >> 4;
  int m0 = blockIdx.x * 128, n0 = blockIdx.y * 128;
  f32x4 acc[4][4] = {};
  for (int ko = 0; ko < 256; ko += 32) {
#pragma unroll
    for (int p = 0; p < 2; p++) {
      int idx = p * 256 + tid;
      int row = idx >> 2, seg = idx & 3;
      int gm = m0 + row; if (gm >= M) gm = M - 1;
      float4 a0 = *(const float4*)(A + (size_t)gm * 256 + ko + seg * 8);
      float4 a1 = *(const float4*)(A + (size_t)gm * 256 + ko + seg * 8 + 4);
      s16x8 av;
      av[0] = (short)f2b(a0.x); av[1] = (short)f2b(a0.y);
      av[2] = (short)f2b(a0.z); av[3] = (short)f2b(a0.w);
      av[4] = (short)f2b(a1.x); av[5] = (short)f2b(a1.y);
      av[6] = (short)f2b(a1.z); av[7] = (short)f2b(a1.w);
      *(s16x8*)&sA[row * 40 + seg * 8] = av;
      *(s16x8*)&sB[row * 40 + seg * 8] = *(const s16x8*)(Bt + (n0 + row) * 256 + ko + seg * 8);
    }
    __syncthreads();
    s16x8 af[4], bf[4];
#pragma unroll
    for (int i = 0; i < 4; i++) af[i] = *(const s16x8*)&sA[(wm * 64 + i * 16 + l15) * 40 + l4 * 8];
#pragma unroll
    for (int j = 0; j < 4; j++) bf[j] = *(const s16x8*)&sB[(wn * 64 + j * 16 + l15) * 40 + l4 * 8];
#pragma unroll
    for (int i = 0; i < 4; i++)
#pragma unroll
      for (int j = 0; j < 4; j++)
        acc[i][j] = __builtin_amdgcn_mfma_f32_16x16x32_bf16(af[i], bf[j], acc[i][j], 0, 0, 0);
    __syncthreads();
  }
#pragma unroll
  for (int j = 0; j < 4; j++) {
    int n = n0 + wn * 64 + j * 16 + l15;
    float bb = bias[n];
    int tpos = ((n & 63) << 3) + (n >> 6);          // head-transposed column
#pragma unroll
    for (int i = 0; i < 4; i++) {
      int mb = m0 + wm * 64 + i * 16 + l4 * 4;
#pragma unroll
      for (int r = 0; r < 4; r++) {
        int m = mb + r;
        if (m < M) C[(size_t)m * 512 + tpos] = f2b(acc[i][j][r] + bb);
      }
    }
  }
}

// ---------------- q/k logits from fp32 x via fused weights ----------------
// xu pass: K0 (FW0 o8..15), Q1 (FW1 o0..7), Q2 (FW2 o0..7), K2 (FW2 o8..15)
__global__ void k_qk_u(const float* __restrict__ x, const float* __restrict__ FW,
                       const float* __restrict__ FB, float* __restrict__ K0,
                       float* __restrict__ Q1, float* __restrict__ Q2,
                       float* __restrict__ K2, int N) {
  int lane = threadIdx.x & 63, wid = threadIdx.x >> 6;
  int stride = gridDim.x * 4;
  for (int row = blockIdx.x * 4 + wid; row < N; row += stride) {
    float4 xv = *(const float4*)(x + (size_t)row * 256 + lane * 4);
    float p[32];
#pragma unroll
    for (int c = 0; c < 32; c++) {
      int o = (c < 8) ? (8 + c) : (c < 16) ? (4096 / 256 * 16 + (c - 8)) : (2 * 16 + (c - 16));
      // o index into FW rows: FW row stride 256; rel offset r*16 rows
      const float4 wv = *(const float4*)(FW + (size_t)((c < 8) ? (8 + c) : (c < 16) ? (16 + (c - 8)) : (32 + (c - 16))) * 256 + lane * 4);
      p[c] = xv.x * wv.x + xv.y * wv.y + xv.z * wv.z + xv.w * wv.w;
      (void)o;
    }
#pragma unroll
    for (int off = 1; off < 64; off <<= 1)
#pragma unroll
      for (int c = 0; c < 32; c++) p[c] += __shfl_xor(p[c], off, 64);
    if (lane == 0) {
#pragma unroll
      for (int c = 0; c < 8; c++) K0[row * 8 + c] = p[c] + FB[8 + c];
#pragma unroll
      for (int c = 0; c < 8; c++) Q1[row * 8 + c] = p[8 + c] + FB[16 + c];
#pragma unroll
      for (int c = 0; c < 8; c++) Q2[row * 8 + c] = p[16 + c] + FB[32 + c];
#pragma unroll
      for (int c = 0; c < 8; c++) K2[row * 8 + c] = p[24 + c] + FB[40 + c];
    }
  }
}

// xi pass: Q0 (FW0 o0..7), K1 (FW1 o8..15)
__global__ void k_qk_i(const float* __restrict__ x, const float* __restrict__ FW,
                       const float* __restrict__ FB, float* __restrict__ Q0,
                       float* __restrict__ K1, int N) {
  int lane = threadIdx.x & 63, wid = threadIdx.x >> 6;
  int stride = gridDim.x * 4;
  for (int row = blockIdx.x * 4 + wid; row < N; row += stride) {
    float4 xv = *(const float4*)(x + (size_t)row * 256 + lane * 4);
    float p[16];
#pragma unroll
    for (int c = 0; c < 16; c++) {
      const float4 wv = *(const float4*)(FW + (size_t)((c < 8) ? c : (16 + c)) * 256 + lane * 4);
      p[c] = xv.x * wv.x + xv.y * wv.y + xv.z * wv.z + xv.w * wv.w;
    }
#pragma unroll
    for (int off = 1; off < 64; off <<= 1)
#pragma unroll
      for (int c = 0; c < 16; c++) p[c] += __shfl_xor(p[c], off, 64);
    if (lane == 0) {
#pragma unroll
      for (int c = 0; c < 8; c++) Q0[row * 8 + c] = p[c] + FB[c];
#pragma unroll
      for (int c = 0; c < 8; c++) K1[row * 8 + c] = p[8 + c] + FB[24 + c];
    }
  }
}

// ---------------- edge aggregation: one wave per dst node (head-transposed H) ----------------
__global__ void __launch_bounds__(256) k_edge(const int* __restrict__ rp, const int* __restrict__ csrc,
                       const float* __restrict__ q, const float* __restrict__ k,
                       const u16* __restrict__ hs, float* __restrict__ out,
                       float scale, int accum) {
  __shared__ float exw[4][64 * 8];
  __shared__ int sarr[4][64];
  int lane = threadIdx.x & 63, w = threadIdx.x >> 6;
  int dst = blockIdx.x * 4 + w;
  if (dst >= NND) return;
  int beg = rp[dst];
  int deg = rp[dst + 1] - beg;
  float qv[8];
  {
    float4 q0 = *(const float4*)(q + dst * 8);
    float4 q1 = *(const float4*)(q + dst * 8 + 4);
    qv[0] = q0.x; qv[1] = q0.y; qv[2] = q0.z; qv[3] = q0.w;
    qv[4] = q1.x; qv[5] = q1.y; qv[6] = q1.z; qv[7] = q1.w;
  }
  float dsum[8] = {0, 0, 0, 0, 0, 0, 0, 0};
  for (int base = 0; base < deg; base += 64) {
    int i = base + lane;
    if (i < deg) {
      int s = csrc[beg + i];
      float4 k0 = *(const float4*)(k + s * 8);
      float4 k1 = *(const float4*)(k + s * 8 + 4);
      float kv[8] = {k0.x, k0.y, k0.z, k0.w, k1.x, k1.y, k1.z, k1.w};
#pragma unroll
      for (int h = 0; h < 8; h++) {
        float e = qv[h] + kv[h];
        e = e > 0.f ? e : 0.2f * e;
        dsum[h] += exp2f(e * 1.44269504f);
      }
    }
  }
#pragma unroll
  for (int off = 1; off < 64; off <<= 1)
#pragma unroll
    for (int h = 0; h < 8; h++) dsum[h] += __shfl_xor(dsum[h], off, 64);
  float rden[8];
#pragma unroll
  for (int h = 0; h < 8; h++) rden[h] = dsum[h] > 0.f ? 1.f / dsum[h] : 0.f;

  float acc8[8] = {0, 0, 0, 0, 0, 0, 0, 0};
  for (int base = 0; base < deg; base += 64) {
    int i = base + lane;
    int nn = min(64, deg - base);
    if (i < deg) {
      int s = csrc[beg + i];
      sarr[w][lane] = s;
      float4 k0 = *(const float4*)(k + s * 8);
      float4 k1 = *(const float4*)(k + s * 8 + 4);
      float kv[8] = {k0.x, k0.y, k0.z, k0.w, k1.x, k1.y, k1.z, k1.w};
#pragma unroll
      for (int h = 0; h < 8; h++) {
        float e = qv[h] + kv[h];
        e = e > 0.f ? e : 0.2f * e;
        exw[w][lane * 8 + h] = exp2f(e * 1.44269504f) * rden[h];
      }
    }
    __asm__ __volatile__("s_waitcnt lgkmcnt(0)" ::: "memory");
    for (int j = 0; j < nn; j++) {
      int s = sarr[w][j];
      s16x8 hv = *(const s16x8*)(hs + (size_t)s * 512 + lane * 8);   // all 8 heads, feature=lane
      float4 e0 = *(const float4*)&exw[w][j * 8];
      float4 e1 = *(const float4*)&exw[w][j * 8 + 4];
      acc8[0] += e0.x * b2f((u16)hv[0]);
      acc8[1] += e0.y * b2f((u16)hv[1]);
      acc8[2] += e0.z * b2f((u16)hv[2]);
      acc8[3] += e0.w * b2f((u16)hv[3]);
      acc8[4] += e1.x * b2f((u16)hv[4]);
      acc8[5] += e1.y * b2f((u16)hv[5]);
      acc8[6] += e1.z * b2f((u16)hv[6]);
      acc8[7] += e1.w * b2f((u16)hv[7]);
    }
  }
  float acc = ((acc8[0] + acc8[1]) + (acc8[2] + acc8[3])) + ((acc8[4] + acc8[5]) + (acc8[6] + acc8[7]));
  acc *= scale;
  if (accum) out[dst * 64 + lane] += acc;
  else out[dst * 64 + lane] = acc;
}

extern "C" void kernel_launch(void* const* d_in, const int* in_sizes, int n_in,
                              void* d_out, int out_size, void* d_ws, size_t ws_size,
                              hipStream_t stream) {
  const float* xu = (const float*)d_in[0];
  const float* xi = (const float*)d_in[1];
  const float* Wv = (const float*)d_in[2];
  const float* bv = (const float*)d_in[3];
  const float* Wq = (const float*)d_in[4];
  const float* bq = (const float*)d_in[5];
  const float* Wk = (const float*)d_in[6];
  const float* bk = (const float*)d_in[7];
  const int* src1 = (const int*)d_in[8];
  const int* dst1 = (const int*)d_in[9];
  const int* src2 = (const int*)d_in[10];
  const int* dst2 = (const int*)d_in[11];
  const int* src3 = (const int*)d_in[12];
  const int* dst3 = (const int*)d_in[13];
  float* out_user = (float*)d_out;
  float* out_item = out_user + (size_t)NND * 64;

  char* w = (char*)d_ws;
  auto alloc = [&](size_t sz) -> char* {
    char* p = w; w += (sz + 255) & ~(size_t)255; return p;
  };
  // total ~83 MB
  u16* H    = (u16*)alloc((size_t)NND * 512 * 2);          // 51.2 MB shared h table
  u16* WT   = (u16*)alloc((size_t)3 * 512 * 256 * 2);      // 0.8 MB
  float* FW = (float*)alloc((size_t)3 * 16 * 256 * 4);     // 49 KB fused qk weights
  float* FB = (float*)alloc((size_t)3 * 16 * 4);
  float* Q0 = (float*)alloc((size_t)NND * 8 * 4);
  float* K0 = (float*)alloc((size_t)NND * 8 * 4);
  float* Q1 = (float*)alloc((size_t)NND * 8 * 4);
  float* K1 = (float*)alloc((size_t)NND * 8 * 4);
  float* Q2 = (float*)alloc((size_t)NND * 8 * 4);
  float* K2 = (float*)alloc((size_t)NND * 8 * 4);          // 9.6 MB total q/k
  int* ROWPTR = (int*)alloc(((size_t)3 * NND + 1) * 4);
  int* BC   = (int*)alloc(TOTB * 4);
  int* BB   = (int*)alloc(TOTB * 4);
  int* BCUR = (int*)alloc(TOTB * 4);
  int* CSRC = (int*)alloc((size_t)3 * EDG * 4);            // 19.2 MB
  unsigned* PAIRS = (unsigned*)H;                          // aliased: dead before H written
  (void)ws_size; (void)n_in; (void)in_sizes; (void)out_size;

  // --- CSR build (bucket partition + per-bucket key sort) ---
  k_zero<<<(TOTB + 255) / 256, 256, 0, stream>>>(BC, TOTB);
  kb_count<<<dim3(256, 3), 256, 0, stream>>>(dst1, dst2, dst3, BC);
  kb_scan<<<1, 1024, 0, stream>>>(BC, BB, BCUR, ROWPTR);
  kb_scatter<<<dim3((EDG + TS - 1) / TS, 3), 256, 0, stream>>>(src1, dst1, src2, dst2, src3, dst3, BCUR, PAIRS);
  kb_build<<<dim3(NBK, 3), 256, 0, stream>>>(PAIRS, BB, BC, ROWPTR, CSRC);

  // --- weight prep ---
  k_prepw<<<(3 * 512 * 256 + 255) / 256, 256, 0, stream>>>(Wv, WT);
  k_fusew<<<48, 256, 0, stream>>>(Wv, bv, Wq, bq, Wk, bk, FW, FB);

  // --- q/k logits (2 fused passes) ---
  k_qk_u<<<1024, 256, 0, stream>>>(xu, FW, FB, K0, Q1, Q2, K2, NND);
  k_qk_i<<<1024, 256, 0, stream>>>(xi, FW, FB, Q0, K1, NND);

  // --- per relation: GEMM into shared H, then edge aggregation ---
  dim3 gg((NND + 127) / 128, 4);
  k_gemm<<<gg, 256, 0, stream>>>(xu, WT,                 bv,        H, NND);
  k_edge<<<NND / 4, 256, 0, stream>>>(ROWPTR,           CSRC, Q0, K0, H, out_item, 0.125f,  0);
  k_gemm<<<gg, 256, 0, stream>>>(xi, WT + 512 * 256,     bv + 512,  H, NND);
  k_edge<<<NND / 4, 256, 0, stream>>>(ROWPTR + NND,     CSRC, Q1, K1, H, out_user, 0.0625f, 0);
  k_gemm<<<gg, 256, 0, stream>>>(xu, WT + 2 * 512 * 256, bv + 1024, H, NND);
  k_edge<<<NND / 4, 256, 0, stream>>>(ROWPTR + 2 * NND, CSRC, Q2, K2, H, out_user, 0.0625f, 1);
}

// Round 5
// 1409.147 us; speedup vs baseline: 1.2840x; 1.2840x over previous
//
#include <hip/hip_runtime.h>

typedef unsigned short u16;
typedef __attribute__((ext_vector_type(4))) float f32x4;
typedef __attribute__((ext_vector_type(8))) short s16x8;

#define NND 50000      // nodes per side (NU == NI)
#define EDG 1600000    // edges per relation
#define NBK 391        // buckets per relation = ceil(NND/128)
#define TOTB (3 * NBK)
#define TS 4096        // edges per scatter tile

__device__ __forceinline__ u16 f2b(float f) {
  union { float f; unsigned u; } c; c.f = f;
  unsigned r = c.u + 0x7fff + ((c.u >> 16) & 1);   // RNE
  return (u16)(r >> 16);
}
__device__ __forceinline__ float b2f(u16 b) {
  union { float f; unsigned u; } c; c.u = ((unsigned)b) << 16; return c.f;
}

// ---------------- zero int buffer ----------------
__global__ void k_zero(int* p, int n) {
  int i = blockIdx.x * 256 + threadIdx.x;
  if (i < n) p[i] = 0;
}

// ---------------- Wt[r][n][kk] = Wv[r][kk][n]  (bf16, 3*512*256) ----------------
__global__ void k_prepw(const float* __restrict__ Wv, u16* __restrict__ Wt) {
  int tid = blockIdx.x * 256 + threadIdx.x;
  if (tid < 3 * 512 * 256) {
    int r = tid / (512 * 256); int rem = tid - r * 512 * 256;
    int n = rem >> 8; int kk = rem & 255;
    Wt[tid] = f2b(Wv[((size_t)r * 256 + kk) * 512 + n]);
  }
}

// ---------------- fused q/k weights ----------------
__global__ void k_fusew(const float* __restrict__ Wv, const float* __restrict__ bv,
                        const float* __restrict__ Wq, const float* __restrict__ bq,
                        const float* __restrict__ Wk, const float* __restrict__ bk,
                        float* __restrict__ FW, float* __restrict__ FB) {
  int tid = blockIdx.x * 256 + threadIdx.x;
  if (tid < 3 * 16 * 256) {
    int r = tid >> 12, o = (tid >> 8) & 15, kk = tid & 255;
    const float* wv = Wv + ((size_t)r * 256 + kk) * 512;
    const float* wqk = (o < 8) ? (Wq + r * 512 * 8 + o) : (Wk + r * 512 * 8 + (o - 8));
    float s = 0.f;
    for (int j = 0; j < 512; j++) s += wv[j] * wqk[j * 8];
    FW[tid] = s;
  }
  if (tid < 48) {
    int r = tid / 16, o = tid % 16;
    const float* wqk = (o < 8) ? (Wq + r * 512 * 8 + o) : (Wk + r * 512 * 8 + (o - 8));
    const float* bvp = bv + r * 512;
    float s = (o < 8) ? bq[r * 8 + o] : bk[r * 8 + (o - 8)];
    for (int j = 0; j < 512; j++) s += bvp[j] * wqk[j * 8];
    FB[tid] = s;
  }
}

// ================= bucket-partitioned CSR build =================
__global__ void kb_count(const int* __restrict__ d1, const int* __restrict__ d2,
                         const int* __restrict__ d3, int* __restrict__ BC) {
  __shared__ int h[NBK];
  int tid = threadIdx.x;
  int r = blockIdx.y;
  const int* d = (r == 0) ? d1 : (r == 1) ? d2 : d3;
  for (int b = tid; b < NBK; b += 256) h[b] = 0;
  __syncthreads();
  for (int e = blockIdx.x * 256 + tid; e < EDG; e += 256 * gridDim.x)
    atomicAdd(&h[d[e] >> 7], 1);
  __syncthreads();
  for (int b = tid; b < NBK; b += 256)
    if (h[b]) atomicAdd(&BC[r * NBK + b], h[b]);
}

__global__ void kb_scan(const int* __restrict__ BC, int* __restrict__ BB,
                        int* __restrict__ BCUR, int* __restrict__ rp) {
  __shared__ int a[2][2048];
  int t = threadIdx.x;   // 1024
  a[0][t]        = (t < TOTB) ? BC[t] : 0;
  a[0][t + 1024] = (t + 1024 < TOTB) ? BC[t + 1024] : 0;
  __syncthreads();
  int s = 0;
  for (int off = 1; off < 2048; off <<= 1) {
    int v0 = a[s][t];        if (t >= off) v0 += a[s][t - off];
    int v1 = a[s][t + 1024]; if (t + 1024 >= off) v1 += a[s][t + 1024 - off];
    __syncthreads();
    a[s ^ 1][t] = v0; a[s ^ 1][t + 1024] = v1;
    __syncthreads();
    s ^= 1;
  }
  if (t < TOTB)        { int e = a[s][t] - BC[t];               BB[t] = e;        BCUR[t] = e; }
  if (t + 1024 < TOTB) { int e = a[s][t + 1024] - BC[t + 1024]; BB[t + 1024] = e; BCUR[t + 1024] = e; }
  if (t == 0) rp[3 * NND] = 3 * EDG;
}

__global__ void __launch_bounds__(256) kb_scatter(
    const int* __restrict__ s1, const int* __restrict__ d1,
    const int* __restrict__ s2, const int* __restrict__ d2,
    const int* __restrict__ s3, const int* __restrict__ d3,
    int* __restrict__ BCUR, unsigned* __restrict__ pairs) {
  __shared__ int h[NBK];
  __shared__ int bbase[NBK];
  int tid = threadIdx.x;
  int r = blockIdx.y;
  const int* dp = (r == 0) ? d1 : (r == 1) ? d2 : d3;
  const int* sp = (r == 0) ? s1 : (r == 1) ? s2 : s3;
  int e0 = blockIdx.x * TS;
  int n = EDG - e0; if (n > TS) n = TS;
  for (int b = tid; b < NBK; b += 256) h[b] = 0;
  __syncthreads();
  int eb[16]; unsigned ev[16];
#pragma unroll
  for (int k = 0; k < 16; k++) {
    int i = k * 256 + tid;
    if (i < n) {
      int d = dp[e0 + i], ss = sp[e0 + i];
      eb[k] = d >> 7;
      ev[k] = ((unsigned)(d & 127) << 16) | (unsigned)ss;
      atomicAdd(&h[eb[k]], 1);
    } else eb[k] = -1;
  }
  __syncthreads();
  for (int b = tid; b < NBK; b += 256) {
    int c = h[b];
    bbase[b] = c ? atomicAdd(&BCUR[r * NBK + b], c) : 0;
  }
  __syncthreads();
  for (int b = tid; b < NBK; b += 256) h[b] = 0;   // reuse as local cursor
  __syncthreads();
#pragma unroll
  for (int k = 0; k < 16; k++) {
    if (eb[k] >= 0) {
      int off = atomicAdd(&h[eb[k]], 1);
      pairs[bbase[eb[k]] + off] = ev[k];
    }
  }
}

// -- per-bucket: group into csrc + emit rowptr (cheap atomic grouping) --
__global__ void __launch_bounds__(256) kb_build(
    const unsigned* __restrict__ pairs, const int* __restrict__ BB,
    const int* __restrict__ BC, int* __restrict__ rp, int* __restrict__ csrc) {
  __shared__ int cntl[128];
  __shared__ int sc[128];
  __shared__ int curl[128];
  int t = threadIdx.x;
  int r = blockIdx.y, bx = blockIdx.x;
  int bin = r * NBK + bx;
  int base = BB[bin], cnt = BC[bin];
  int node0 = bx << 7;
  int nloc = NND - node0; if (nloc > 128) nloc = 128;
  if (t < 128) cntl[t] = 0;
  __syncthreads();
  for (int i = t; i < cnt; i += 256)
    atomicAdd(&cntl[pairs[base + i] >> 16], 1);
  __syncthreads();
  if (t < 128) sc[t] = cntl[t];
  __syncthreads();
  for (int off = 1; off < 128; off <<= 1) {
    int v = 0;
    if (t < 128) { v = sc[t]; if (t >= off) v += sc[t - off]; }
    __syncthreads();
    if (t < 128) sc[t] = v;
    __syncthreads();
  }
  if (t < 128) {
    int excl = sc[t] - cntl[t];
    if (t < nloc) rp[r * NND + node0 + t] = base + excl;
    curl[t] = base + excl;
  }
  __syncthreads();
  for (int i = t; i < cnt; i += 256) {
    unsigned v = pairs[base + i];
    int p = atomicAdd(&curl[v >> 16], 1);
    csrc[p] = (int)(v & 0xFFFFu);
  }
}

// ---------------- bf16 MFMA GEMM: H[M][f*8+h] = bf16(A_f32[M,256] @ Wv + bv)  (head-transposed) ----------------
__global__ void __launch_bounds__(256) k_gemm(const float* __restrict__ A, const u16* __restrict__ Bt,
                                              const float* __restrict__ bias, u16* __restrict__ C, int M) {
  __shared__ u16 sA[128 * 40];
  __shared__ u16 sB[128 * 40];
  int tid = threadIdx.x;
  int lane = tid & 63, wid = tid >> 6;
  int wm = wid >> 1, wn = wid & 1;
  int l15 = lane & 15, l4 = lane >> 4;
  int m0 = blockIdx.x * 128, n0 = blockIdx.y * 128;
  f32x4 acc[4][4] = {};
  for (int ko = 0; ko < 256; ko += 32) {
#pragma unroll
    for (int p = 0; p < 2; p++) {
      int idx = p * 256 + tid;
      int row = idx >> 2, seg = idx & 3;
      int gm = m0 + row; if (gm >= M) gm = M - 1;
      float4 a0 = *(const float4*)(A + (size_t)gm * 256 + ko + seg * 8);
      float4 a1 = *(const float4*)(A + (size_t)gm * 256 + ko + seg * 8 + 4);
      s16x8 av;
      av[0] = (short)f2b(a0.x); av[1] = (short)f2b(a0.y);
      av[2] = (short)f2b(a0.z); av[3] = (short)f2b(a0.w);
      av[4] = (short)f2b(a1.x); av[5] = (short)f2b(a1.y);
      av[6] = (short)f2b(a1.z); av[7] = (short)f2b(a1.w);
      *(s16x8*)&sA[row * 40 + seg * 8] = av;
      *(s16x8*)&sB[row * 40 + seg * 8] = *(const s16x8*)(Bt + (n0 + row) * 256 + ko + seg * 8);
    }
    __syncthreads();
    s16x8 af[4], bf[4];
#pragma unroll
    for (int i = 0; i < 4; i++) af[i] = *(const s16x8*)&sA[(wm * 64 + i * 16 + l15) * 40 + l4 * 8];
#pragma unroll
    for (int j = 0; j < 4; j++) bf[j] = *(const s16x8*)&sB[(wn * 64 + j * 16 + l15) * 40 + l4 * 8];
#pragma unroll
    for (int i = 0; i < 4; i++)
#pragma unroll
      for (int j = 0; j < 4; j++)
        acc[i][j] = __builtin_amdgcn_mfma_f32_16x16x32_bf16(af[i], bf[j], acc[i][j], 0, 0, 0);
    __syncthreads();
  }
#pragma unroll
  for (int j = 0; j < 4; j++) {
    int n = n0 + wn * 64 + j * 16 + l15;
    float bb = bias[n];
    int tpos = ((n & 63) << 3) + (n >> 6);          // head-transposed column
#pragma unroll
    for (int i = 0; i < 4; i++) {
      int mb = m0 + wm * 64 + i * 16 + l4 * 4;
#pragma unroll
      for (int r = 0; r < 4; r++) {
        int m = mb + r;
        if (m < M) C[(size_t)m * 512 + tpos] = f2b(acc[i][j][r] + bb);
      }
    }
  }
}

// ---------------- q/k logits from fp32 x via fused weights ----------------
// xu pass: K0 (rel0 o8..15), Q1 (rel1 o0..7), Q2 (rel2 o0..7), K2 (rel2 o8..15)
__global__ void k_qk_u(const float* __restrict__ x, const float* __restrict__ FW,
                       const float* __restrict__ FB, float* __restrict__ K0,
                       float* __restrict__ Q1, float* __restrict__ Q2,
                       float* __restrict__ K2, int N) {
  int lane = threadIdx.x & 63, wid = threadIdx.x >> 6;
  int stride = gridDim.x * 4;
  for (int row = blockIdx.x * 4 + wid; row < N; row += stride) {
    float4 xv = *(const float4*)(x + (size_t)row * 256 + lane * 4);
    float p[32];
#pragma unroll
    for (int c = 0; c < 32; c++) {
      int fwrow = (c < 8) ? (8 + c) : (c < 16) ? (16 + (c - 8)) : (c < 24) ? (32 + (c - 16)) : (40 + (c - 24));
      const float4 wv = *(const float4*)(FW + (size_t)fwrow * 256 + lane * 4);
      p[c] = xv.x * wv.x + xv.y * wv.y + xv.z * wv.z + xv.w * wv.w;
    }
#pragma unroll
    for (int off = 1; off < 64; off <<= 1)
#pragma unroll
      for (int c = 0; c < 32; c++) p[c] += __shfl_xor(p[c], off, 64);
    if (lane == 0) {
#pragma unroll
      for (int c = 0; c < 8; c++) K0[row * 8 + c] = p[c] + FB[8 + c];
#pragma unroll
      for (int c = 0; c < 8; c++) Q1[row * 8 + c] = p[8 + c] + FB[16 + c];
#pragma unroll
      for (int c = 0; c < 8; c++) Q2[row * 8 + c] = p[16 + c] + FB[32 + c];
#pragma unroll
      for (int c = 0; c < 8; c++) K2[row * 8 + c] = p[24 + c] + FB[40 + c];
    }
  }
}

// xi pass: Q0 (rel0 o0..7), K1 (rel1 o8..15)
__global__ void k_qk_i(const float* __restrict__ x, const float* __restrict__ FW,
                       const float* __restrict__ FB, float* __restrict__ Q0,
                       float* __restrict__ K1, int N) {
  int lane = threadIdx.x & 63, wid = threadIdx.x >> 6;
  int stride = gridDim.x * 4;
  for (int row = blockIdx.x * 4 + wid; row < N; row += stride) {
    float4 xv = *(const float4*)(x + (size_t)row * 256 + lane * 4);
    float p[16];
#pragma unroll
    for (int c = 0; c < 16; c++) {
      const float4 wv = *(const float4*)(FW + (size_t)((c < 8) ? c : (16 + c)) * 256 + lane * 4);
      p[c] = xv.x * wv.x + xv.y * wv.y + xv.z * wv.z + xv.w * wv.w;
    }
#pragma unroll
    for (int off = 1; off < 64; off <<= 1)
#pragma unroll
      for (int c = 0; c < 16; c++) p[c] += __shfl_xor(p[c], off, 64);
    if (lane == 0) {
#pragma unroll
      for (int c = 0; c < 8; c++) Q0[row * 8 + c] = p[c] + FB[c];
#pragma unroll
      for (int c = 0; c < 8; c++) K1[row * 8 + c] = p[8 + c] + FB[24 + c];
    }
  }
}

// ---------------- edge aggregation: TWO waves per dst (halved serial chain) ----------------
__global__ void __launch_bounds__(256) k_edge(const int* __restrict__ rp, const int* __restrict__ csrc,
                       const float* __restrict__ q, const float* __restrict__ k,
                       const u16* __restrict__ hs, float* __restrict__ out,
                       float scale, int accum) {
  __shared__ float exw[4][64 * 8];
  __shared__ int sarr[4][64];
  __shared__ float sd[4][8];
  __shared__ float sacc[4][64];
  int lane = threadIdx.x & 63, w = threadIdx.x >> 6;
  int dst = blockIdx.x * 2 + (w >> 1);
  int half = w & 1;
  int beg = rp[dst];
  int deg = rp[dst + 1] - beg;
  int hlen = (deg + 1) >> 1;
  int s0 = half ? hlen : 0;
  int s1 = half ? deg : hlen;
  float qv[8];
  {
    float4 q0 = *(const float4*)(q + dst * 8);
    float4 q1 = *(const float4*)(q + dst * 8 + 4);
    qv[0] = q0.x; qv[1] = q0.y; qv[2] = q0.z; qv[3] = q0.w;
    qv[4] = q1.x; qv[5] = q1.y; qv[6] = q1.z; qv[7] = q1.w;
  }
  // pass A: partial softmax denominators over this wave's half
  float dsum[8] = {0, 0, 0, 0, 0, 0, 0, 0};
  for (int i = s0 + lane; i < s1; i += 64) {
    int s = csrc[beg + i];
    float4 k0 = *(const float4*)(k + s * 8);
    float4 k1 = *(const float4*)(k + s * 8 + 4);
    float kv[8] = {k0.x, k0.y, k0.z, k0.w, k1.x, k1.y, k1.z, k1.w};
#pragma unroll
    for (int h = 0; h < 8; h++) {
      float e = qv[h] + kv[h];
      e = e > 0.f ? e : 0.2f * e;
      dsum[h] += exp2f(e * 1.44269504f);
    }
  }
#pragma unroll
  for (int off = 1; off < 64; off <<= 1)
#pragma unroll
    for (int h = 0; h < 8; h++) dsum[h] += __shfl_xor(dsum[h], off, 64);
  if (lane == 0) {
#pragma unroll
    for (int h = 0; h < 8; h++) sd[w][h] = dsum[h];
  }
  __syncthreads();
  float rden[8];
#pragma unroll
  for (int h = 0; h < 8; h++) {
    float tot = sd[w][h] + sd[w ^ 1][h];
    rden[h] = tot > 0.f ? 1.f / tot : 0.f;
  }

  // pass B: weighted gather over this wave's half
  float acc8[8] = {0, 0, 0, 0, 0, 0, 0, 0};
  for (int base = s0; base < s1; base += 64) {
    int i = base + lane;
    int nn = min(64, s1 - base);
    if (i < s1) {
      int s = csrc[beg + i];
      sarr[w][lane] = s;
      float4 k0 = *(const float4*)(k + s * 8);
      float4 k1 = *(const float4*)(k + s * 8 + 4);
      float kv[8] = {k0.x, k0.y, k0.z, k0.w, k1.x, k1.y, k1.z, k1.w};
#pragma unroll
      for (int h = 0; h < 8; h++) {
        float e = qv[h] + kv[h];
        e = e > 0.f ? e : 0.2f * e;
        exw[w][lane * 8 + h] = exp2f(e * 1.44269504f) * rden[h];
      }
    }
    __asm__ __volatile__("s_waitcnt lgkmcnt(0)" ::: "memory");
    for (int j = 0; j < nn; j++) {
      int s = sarr[w][j];
      s16x8 hv = *(const s16x8*)(hs + (size_t)s * 512 + lane * 8);   // all 8 heads, feature=lane
      float4 e0 = *(const float4*)&exw[w][j * 8];
      float4 e1 = *(const float4*)&exw[w][j * 8 + 4];
      acc8[0] += e0.x * b2f((u16)hv[0]);
      acc8[1] += e0.y * b2f((u16)hv[1]);
      acc8[2] += e0.z * b2f((u16)hv[2]);
      acc8[3] += e0.w * b2f((u16)hv[3]);
      acc8[4] += e1.x * b2f((u16)hv[4]);
      acc8[5] += e1.y * b2f((u16)hv[5]);
      acc8[6] += e1.z * b2f((u16)hv[6]);
      acc8[7] += e1.w * b2f((u16)hv[7]);
    }
  }
  float acc = ((acc8[0] + acc8[1]) + (acc8[2] + acc8[3])) + ((acc8[4] + acc8[5]) + (acc8[6] + acc8[7]));
  acc *= scale;
  sacc[w][lane] = acc;
  __syncthreads();
  if (half == 0) {
    float tot = sacc[w][lane] + sacc[w + 1][lane];
    if (accum) out[dst * 64 + lane] += tot;
    else out[dst * 64 + lane] = tot;
  }
}

extern "C" void kernel_launch(void* const* d_in, const int* in_sizes, int n_in,
                              void* d_out, int out_size, void* d_ws, size_t ws_size,
                              hipStream_t stream) {
  const float* xu = (const float*)d_in[0];
  const float* xi = (const float*)d_in[1];
  const float* Wv = (const float*)d_in[2];
  const float* bv = (const float*)d_in[3];
  const float* Wq = (const float*)d_in[4];
  const float* bq = (const float*)d_in[5];
  const float* Wk = (const float*)d_in[6];
  const float* bk = (const float*)d_in[7];
  const int* src1 = (const int*)d_in[8];
  const int* dst1 = (const int*)d_in[9];
  const int* src2 = (const int*)d_in[10];
  const int* dst2 = (const int*)d_in[11];
  const int* src3 = (const int*)d_in[12];
  const int* dst3 = (const int*)d_in[13];
  float* out_user = (float*)d_out;
  float* out_item = out_user + (size_t)NND * 64;

  char* w = (char*)d_ws;
  auto alloc = [&](size_t sz) -> char* {
    char* p = w; w += (sz + 255) & ~(size_t)255; return p;
  };
  // total ~83 MB
  u16* H    = (u16*)alloc((size_t)NND * 512 * 2);          // 51.2 MB shared h table
  u16* WT   = (u16*)alloc((size_t)3 * 512 * 256 * 2);      // 0.8 MB
  float* FW = (float*)alloc((size_t)3 * 16 * 256 * 4);     // 49 KB fused qk weights
  float* FB = (float*)alloc((size_t)3 * 16 * 4);
  float* Q0 = (float*)alloc((size_t)NND * 8 * 4);
  float* K0 = (float*)alloc((size_t)NND * 8 * 4);
  float* Q1 = (float*)alloc((size_t)NND * 8 * 4);
  float* K1 = (float*)alloc((size_t)NND * 8 * 4);
  float* Q2 = (float*)alloc((size_t)NND * 8 * 4);
  float* K2 = (float*)alloc((size_t)NND * 8 * 4);          // 9.6 MB total q/k
  int* ROWPTR = (int*)alloc(((size_t)3 * NND + 1) * 4);
  int* BC   = (int*)alloc(TOTB * 4);
  int* BB   = (int*)alloc(TOTB * 4);
  int* BCUR = (int*)alloc(TOTB * 4);
  int* CSRC = (int*)alloc((size_t)3 * EDG * 4);            // 19.2 MB
  unsigned* PAIRS = (unsigned*)H;                          // aliased: dead before H written
  (void)ws_size; (void)n_in; (void)in_sizes; (void)out_size;

  // --- CSR build (bucket partition, cheap grouping) ---
  k_zero<<<(TOTB + 255) / 256, 256, 0, stream>>>(BC, TOTB);
  kb_count<<<dim3(256, 3), 256, 0, stream>>>(dst1, dst2, dst3, BC);
  kb_scan<<<1, 1024, 0, stream>>>(BC, BB, BCUR, ROWPTR);
  kb_scatter<<<dim3((EDG + TS - 1) / TS, 3), 256, 0, stream>>>(src1, dst1, src2, dst2, src3, dst3, BCUR, PAIRS);
  kb_build<<<dim3(NBK, 3), 256, 0, stream>>>(PAIRS, BB, BC, ROWPTR, CSRC);

  // --- weight prep ---
  k_prepw<<<(3 * 512 * 256 + 255) / 256, 256, 0, stream>>>(Wv, WT);
  k_fusew<<<48, 256, 0, stream>>>(Wv, bv, Wq, bq, Wk, bk, FW, FB);

  // --- q/k logits (2 fused passes) ---
  k_qk_u<<<1024, 256, 0, stream>>>(xu, FW, FB, K0, Q1, Q2, K2, NND);
  k_qk_i<<<1024, 256, 0, stream>>>(xi, FW, FB, Q0, K1, NND);

  // --- per relation: GEMM into shared H, then edge aggregation ---
  dim3 gg((NND + 127) / 128, 4);
  k_gemm<<<gg, 256, 0, stream>>>(xu, WT,                 bv,        H, NND);
  k_edge<<<NND / 2, 256, 0, stream>>>(ROWPTR,           CSRC, Q0, K0, H, out_item, 0.125f,  0);
  k_gemm<<<gg, 256, 0, stream>>>(xi, WT + 512 * 256,     bv + 512,  H, NND);
  k_edge<<<NND / 2, 256, 0, stream>>>(ROWPTR + NND,     CSRC, Q1, K1, H, out_user, 0.0625f, 0);
  k_gemm<<<gg, 256, 0, stream>>>(xu, WT + 2 * 512 * 256, bv + 1024, H, NND);
  k_edge<<<NND / 2, 256, 0, stream>>>(ROWPTR + 2 * NND, CSRC, Q2, K2, H, out_user, 0.0625f, 1);
}

// Round 6
// 1251.448 us; speedup vs baseline: 1.4458x; 1.1260x over previous
//
#include <hip/hip_runtime.h>

typedef unsigned short u16;
typedef __attribute__((ext_vector_type(4))) float f32x4;
typedef __attribute__((ext_vector_type(8))) short s16x8;

#define NND 50000      // nodes per side (NU == NI)
#define EDG 1600000    // edges per relation
#define NBK 391        // buckets per relation = ceil(NND/128)
#define TOTB (3 * NBK)
#define TS 4096        // edges per scatter tile

__device__ __forceinline__ u16 f2b(float f) {
  union { float f; unsigned u; } c; c.f = f;
  unsigned r = c.u + 0x7fff + ((c.u >> 16) & 1);   // RNE
  return (u16)(r >> 16);
}
__device__ __forceinline__ float b2f(u16 b) {
  union { float f; unsigned u; } c; c.u = ((unsigned)b) << 16; return c.f;
}

// ---------------- zero int buffer ----------------
__global__ void k_zero(int* p, int n) {
  int i = blockIdx.x * 256 + threadIdx.x;
  if (i < n) p[i] = 0;
}

// ---------------- Wt[r][n][kk] = Wv[r][kk][n]  (bf16, 3*512*256) ----------------
__global__ void k_prepw(const float* __restrict__ Wv, u16* __restrict__ Wt) {
  int tid = blockIdx.x * 256 + threadIdx.x;
  if (tid < 3 * 512 * 256) {
    int r = tid / (512 * 256); int rem = tid - r * 512 * 256;
    int n = rem >> 8; int kk = rem & 255;
    Wt[tid] = f2b(Wv[((size_t)r * 256 + kk) * 512 + n]);
  }
}

// ---------------- fused q/k weights ----------------
__global__ void k_fusew(const float* __restrict__ Wv, const float* __restrict__ bv,
                        const float* __restrict__ Wq, const float* __restrict__ bq,
                        const float* __restrict__ Wk, const float* __restrict__ bk,
                        float* __restrict__ FW, float* __restrict__ FB) {
  int tid = blockIdx.x * 256 + threadIdx.x;
  if (tid < 3 * 16 * 256) {
    int r = tid >> 12, o = (tid >> 8) & 15, kk = tid & 255;
    const float* wv = Wv + ((size_t)r * 256 + kk) * 512;
    const float* wqk = (o < 8) ? (Wq + r * 512 * 8 + o) : (Wk + r * 512 * 8 + (o - 8));
    float s = 0.f;
    for (int j = 0; j < 512; j++) s += wv[j] * wqk[j * 8];
    FW[tid] = s;
  }
  if (tid < 48) {
    int r = tid / 16, o = tid % 16;
    const float* wqk = (o < 8) ? (Wq + r * 512 * 8 + o) : (Wk + r * 512 * 8 + (o - 8));
    const float* bvp = bv + r * 512;
    float s = (o < 8) ? bq[r * 8 + o] : bk[r * 8 + (o - 8)];
    for (int j = 0; j < 512; j++) s += bvp[j] * wqk[j * 8];
    FB[tid] = s;
  }
}

// ================= bucket-partitioned CSR build =================
__global__ void kb_count(const int* __restrict__ d1, const int* __restrict__ d2,
                         const int* __restrict__ d3, int* __restrict__ BC) {
  __shared__ int h[NBK];
  int tid = threadIdx.x;
  int r = blockIdx.y;
  const int* d = (r == 0) ? d1 : (r == 1) ? d2 : d3;
  for (int b = tid; b < NBK; b += 256) h[b] = 0;
  __syncthreads();
  for (int e = blockIdx.x * 256 + tid; e < EDG; e += 256 * gridDim.x)
    atomicAdd(&h[d[e] >> 7], 1);
  __syncthreads();
  for (int b = tid; b < NBK; b += 256)
    if (h[b]) atomicAdd(&BC[r * NBK + b], h[b]);
}

__global__ void kb_scan(const int* __restrict__ BC, int* __restrict__ BB,
                        int* __restrict__ BCUR, int* __restrict__ rp) {
  __shared__ int a[2][2048];
  int t = threadIdx.x;   // 1024
  a[0][t]        = (t < TOTB) ? BC[t] : 0;
  a[0][t + 1024] = (t + 1024 < TOTB) ? BC[t + 1024] : 0;
  __syncthreads();
  int s = 0;
  for (int off = 1; off < 2048; off <<= 1) {
    int v0 = a[s][t];        if (t >= off) v0 += a[s][t - off];
    int v1 = a[s][t + 1024]; if (t + 1024 >= off) v1 += a[s][t + 1024 - off];
    __syncthreads();
    a[s ^ 1][t] = v0; a[s ^ 1][t + 1024] = v1;
    __syncthreads();
    s ^= 1;
  }
  if (t < TOTB)        { int e = a[s][t] - BC[t];               BB[t] = e;        BCUR[t] = e; }
  if (t + 1024 < TOTB) { int e = a[s][t + 1024] - BC[t + 1024]; BB[t + 1024] = e; BCUR[t + 1024] = e; }
  if (t == 0) rp[3 * NND] = 3 * EDG;
}

__global__ void __launch_bounds__(256) kb_scatter(
    const int* __restrict__ s1, const int* __restrict__ d1,
    const int* __restrict__ s2, const int* __restrict__ d2,
    const int* __restrict__ s3, const int* __restrict__ d3,
    int* __restrict__ BCUR, unsigned* __restrict__ pairs) {
  __shared__ int h[NBK];
  __shared__ int bbase[NBK];
  int tid = threadIdx.x;
  int r = blockIdx.y;
  const int* dp = (r == 0) ? d1 : (r == 1) ? d2 : d3;
  const int* sp = (r == 0) ? s1 : (r == 1) ? s2 : s3;
  int e0 = blockIdx.x * TS;
  int n = EDG - e0; if (n > TS) n = TS;
  for (int b = tid; b < NBK; b += 256) h[b] = 0;
  __syncthreads();
  int eb[16]; unsigned ev[16];
#pragma unroll
  for (int k = 0; k < 16; k++) {
    int i = k * 256 + tid;
    if (i < n) {
      int d = dp[e0 + i], ss = sp[e0 + i];
      eb[k] = d >> 7;
      ev[k] = ((unsigned)(d & 127) << 16) | (unsigned)ss;
      atomicAdd(&h[eb[k]], 1);
    } else eb[k] = -1;
  }
  __syncthreads();
  for (int b = tid; b < NBK; b += 256) {
    int c = h[b];
    bbase[b] = c ? atomicAdd(&BCUR[r * NBK + b], c) : 0;
  }
  __syncthreads();
  for (int b = tid; b < NBK; b += 256) h[b] = 0;   // reuse as local cursor
  __syncthreads();
#pragma unroll
  for (int k = 0; k < 16; k++) {
    if (eb[k] >= 0) {
      int off = atomicAdd(&h[eb[k]], 1);
      pairs[bbase[eb[k]] + off] = ev[k];
    }
  }
}

// -- per-bucket: group into csrc + emit rowptr (cheap atomic grouping) --
__global__ void __launch_bounds__(256) kb_build(
    const unsigned* __restrict__ pairs, const int* __restrict__ BB,
    const int* __restrict__ BC, int* __restrict__ rp, int* __restrict__ csrc) {
  __shared__ int cntl[128];
  __shared__ int sc[128];
  __shared__ int curl[128];
  int t = threadIdx.x;
  int r = blockIdx.y, bx = blockIdx.x;
  int bin = r * NBK + bx;
  int base = BB[bin], cnt = BC[bin];
  int node0 = bx << 7;
  int nloc = NND - node0; if (nloc > 128) nloc = 128;
  if (t < 128) cntl[t] = 0;
  __syncthreads();
  for (int i = t; i < cnt; i += 256)
    atomicAdd(&cntl[pairs[base + i] >> 16], 1);
  __syncthreads();
  if (t < 128) sc[t] = cntl[t];
  __syncthreads();
  for (int off = 1; off < 128; off <<= 1) {
    int v = 0;
    if (t < 128) { v = sc[t]; if (t >= off) v += sc[t - off]; }
    __syncthreads();
    if (t < 128) sc[t] = v;
    __syncthreads();
  }
  if (t < 128) {
    int excl = sc[t] - cntl[t];
    if (t < nloc) rp[r * NND + node0 + t] = base + excl;
    curl[t] = base + excl;
  }
  __syncthreads();
  for (int i = t; i < cnt; i += 256) {
    unsigned v = pairs[base + i];
    int p = atomicAdd(&curl[v >> 16], 1);
    csrc[p] = (int)(v & 0xFFFFu);
  }
}

// ---------------- bf16 MFMA GEMM: H[M][f*8+h] = bf16(A_f32[M,256] @ Wv + bv)  (head-transposed) ----------------
__global__ void __launch_bounds__(256) k_gemm(const float* __restrict__ A, const u16* __restrict__ Bt,
                                              const float* __restrict__ bias, u16* __restrict__ C, int M) {
  __shared__ u16 sA[128 * 40];
  __shared__ u16 sB[128 * 40];
  int tid = threadIdx.x;
  int lane = tid & 63, wid = tid >> 6;
  int wm = wid >> 1, wn = wid & 1;
  int l15 = lane & 15, l4 = lane >> 4;
  int m0 = blockIdx.x * 128, n0 = blockIdx.y * 128;
  f32x4 acc[4][4] = {};
  for (int ko = 0; ko < 256; ko += 32) {
#pragma unroll
    for (int p = 0; p < 2; p++) {
      int idx = p * 256 + tid;
      int row = idx >> 2, seg = idx & 3;
      int gm = m0 + row; if (gm >= M) gm = M - 1;
      float4 a0 = *(const float4*)(A + (size_t)gm * 256 + ko + seg * 8);
      float4 a1 = *(const float4*)(A + (size_t)gm * 256 + ko + seg * 8 + 4);
      s16x8 av;
      av[0] = (short)f2b(a0.x); av[1] = (short)f2b(a0.y);
      av[2] = (short)f2b(a0.z); av[3] = (short)f2b(a0.w);
      av[4] = (short)f2b(a1.x); av[5] = (short)f2b(a1.y);
      av[6] = (short)f2b(a1.z); av[7] = (short)f2b(a1.w);
      *(s16x8*)&sA[row * 40 + seg * 8] = av;
      *(s16x8*)&sB[row * 40 + seg * 8] = *(const s16x8*)(Bt + (n0 + row) * 256 + ko + seg * 8);
    }
    __syncthreads();
    s16x8 af[4], bf[4];
#pragma unroll
    for (int i = 0; i < 4; i++) af[i] = *(const s16x8*)&sA[(wm * 64 + i * 16 + l15) * 40 + l4 * 8];
#pragma unroll
    for (int j = 0; j < 4; j++) bf[j] = *(const s16x8*)&sB[(wn * 64 + j * 16 + l15) * 40 + l4 * 8];
#pragma unroll
    for (int i = 0; i < 4; i++)
#pragma unroll
      for (int j = 0; j < 4; j++)
        acc[i][j] = __builtin_amdgcn_mfma_f32_16x16x32_bf16(af[i], bf[j], acc[i][j], 0, 0, 0);
    __syncthreads();
  }
#pragma unroll
  for (int j = 0; j < 4; j++) {
    int n = n0 + wn * 64 + j * 16 + l15;
    float bb = bias[n];
    int tpos = ((n & 63) << 3) + (n >> 6);          // head-transposed column
#pragma unroll
    for (int i = 0; i < 4; i++) {
      int mb = m0 + wm * 64 + i * 16 + l4 * 4;
#pragma unroll
      for (int r = 0; r < 4; r++) {
        int m = mb + r;
        if (m < M) C[(size_t)m * 512 + tpos] = f2b(acc[i][j][r] + bb);
      }
    }
  }
}

// ---------------- q/k logits from fp32 x via fused weights ----------------
// Two groups of 16 outputs kept live at a time: spill-free at any VGPR cap.
// xu pass: group A = K0 (rows 8..15), Q1 (16..23); group B = Q2 (32..39), K2 (40..47)
__global__ void __launch_bounds__(256) k_qk_u(
    const float* __restrict__ x, const float* __restrict__ FW,
    const float* __restrict__ FB, float* __restrict__ K0,
    float* __restrict__ Q1, float* __restrict__ Q2,
    float* __restrict__ K2, int N) {
  int lane = threadIdx.x & 63, wid = threadIdx.x >> 6;
  int stride = gridDim.x * 4;
  for (int row = blockIdx.x * 4 + wid; row < N; row += stride) {
    float4 xv = *(const float4*)(x + (size_t)row * 256 + lane * 4);
    // group A: FW rows 8..23
    {
      float p[16];
#pragma unroll
      for (int c = 0; c < 16; c++) {
        const float4 wv = *(const float4*)(FW + (size_t)(8 + c) * 256 + lane * 4);
        p[c] = xv.x * wv.x + xv.y * wv.y + xv.z * wv.z + xv.w * wv.w;
      }
#pragma unroll
      for (int off = 1; off < 64; off <<= 1)
#pragma unroll
        for (int c = 0; c < 16; c++) p[c] += __shfl_xor(p[c], off, 64);
      if (lane == 0) {
#pragma unroll
        for (int c = 0; c < 8; c++) K0[row * 8 + c] = p[c] + FB[8 + c];
#pragma unroll
        for (int c = 0; c < 8; c++) Q1[row * 8 + c] = p[8 + c] + FB[16 + c];
      }
    }
    // group B: FW rows 32..47
    {
      float p[16];
#pragma unroll
      for (int c = 0; c < 16; c++) {
        const float4 wv = *(const float4*)(FW + (size_t)(32 + c) * 256 + lane * 4);
        p[c] = xv.x * wv.x + xv.y * wv.y + xv.z * wv.z + xv.w * wv.w;
      }
#pragma unroll
      for (int off = 1; off < 64; off <<= 1)
#pragma unroll
        for (int c = 0; c < 16; c++) p[c] += __shfl_xor(p[c], off, 64);
      if (lane == 0) {
#pragma unroll
        for (int c = 0; c < 8; c++) Q2[row * 8 + c] = p[c] + FB[32 + c];
#pragma unroll
        for (int c = 0; c < 8; c++) K2[row * 8 + c] = p[8 + c] + FB[40 + c];
      }
    }
  }
}

// xi pass: Q0 (rows 0..7), K1 (rows 24..31)
__global__ void __launch_bounds__(256) k_qk_i(
    const float* __restrict__ x, const float* __restrict__ FW,
    const float* __restrict__ FB, float* __restrict__ Q0,
    float* __restrict__ K1, int N) {
  int lane = threadIdx.x & 63, wid = threadIdx.x >> 6;
  int stride = gridDim.x * 4;
  for (int row = blockIdx.x * 4 + wid; row < N; row += stride) {
    float4 xv = *(const float4*)(x + (size_t)row * 256 + lane * 4);
    float p[16];
#pragma unroll
    for (int c = 0; c < 16; c++) {
      const float4 wv = *(const float4*)(FW + (size_t)((c < 8) ? c : (16 + c)) * 256 + lane * 4);
      p[c] = xv.x * wv.x + xv.y * wv.y + xv.z * wv.z + xv.w * wv.w;
    }
#pragma unroll
    for (int off = 1; off < 64; off <<= 1)
#pragma unroll
      for (int c = 0; c < 16; c++) p[c] += __shfl_xor(p[c], off, 64);
    if (lane == 0) {
#pragma unroll
      for (int c = 0; c < 8; c++) Q0[row * 8 + c] = p[c] + FB[c];
#pragma unroll
      for (int c = 0; c < 8; c++) K1[row * 8 + c] = p[8 + c] + FB[24 + c];
    }
  }
}

// ---------------- edge aggregation: TWO waves per dst (halved serial chain) ----------------
__global__ void __launch_bounds__(256) k_edge(const int* __restrict__ rp, const int* __restrict__ csrc,
                       const float* __restrict__ q, const float* __restrict__ k,
                       const u16* __restrict__ hs, float* __restrict__ out,
                       float scale, int accum) {
  __shared__ float exw[4][64 * 8];
  __shared__ int sarr[4][64];
  __shared__ float sd[4][8];
  __shared__ float sacc[4][64];
  int lane = threadIdx.x & 63, w = threadIdx.x >> 6;
  int dst = blockIdx.x * 2 + (w >> 1);
  int half = w & 1;
  int beg = rp[dst];
  int deg = rp[dst + 1] - beg;
  int hlen = (deg + 1) >> 1;
  int s0 = half ? hlen : 0;
  int s1 = half ? deg : hlen;
  float qv[8];
  {
    float4 q0 = *(const float4*)(q + dst * 8);
    float4 q1 = *(const float4*)(q + dst * 8 + 4);
    qv[0] = q0.x; qv[1] = q0.y; qv[2] = q0.z; qv[3] = q0.w;
    qv[4] = q1.x; qv[5] = q1.y; qv[6] = q1.z; qv[7] = q1.w;
  }
  // pass A: partial softmax denominators over this wave's half
  float dsum[8] = {0, 0, 0, 0, 0, 0, 0, 0};
  for (int i = s0 + lane; i < s1; i += 64) {
    int s = csrc[beg + i];
    float4 k0 = *(const float4*)(k + s * 8);
    float4 k1 = *(const float4*)(k + s * 8 + 4);
    float kv[8] = {k0.x, k0.y, k0.z, k0.w, k1.x, k1.y, k1.z, k1.w};
#pragma unroll
    for (int h = 0; h < 8; h++) {
      float e = qv[h] + kv[h];
      e = e > 0.f ? e : 0.2f * e;
      dsum[h] += exp2f(e * 1.44269504f);
    }
  }
#pragma unroll
  for (int off = 1; off < 64; off <<= 1)
#pragma unroll
    for (int h = 0; h < 8; h++) dsum[h] += __shfl_xor(dsum[h], off, 64);
  if (lane == 0) {
#pragma unroll
    for (int h = 0; h < 8; h++) sd[w][h] = dsum[h];
  }
  __syncthreads();
  float rden[8];
#pragma unroll
  for (int h = 0; h < 8; h++) {
    float tot = sd[w][h] + sd[w ^ 1][h];
    rden[h] = tot > 0.f ? 1.f / tot : 0.f;
  }

  // pass B: weighted gather over this wave's half
  float acc8[8] = {0, 0, 0, 0, 0, 0, 0, 0};
  for (int base = s0; base < s1; base += 64) {
    int i = base + lane;
    int nn = min(64, s1 - base);
    if (i < s1) {
      int s = csrc[beg + i];
      sarr[w][lane] = s;
      float4 k0 = *(const float4*)(k + s * 8);
      float4 k1 = *(const float4*)(k + s * 8 + 4);
      float kv[8] = {k0.x, k0.y, k0.z, k0.w, k1.x, k1.y, k1.z, k1.w};
#pragma unroll
      for (int h = 0; h < 8; h++) {
        float e = qv[h] + kv[h];
        e = e > 0.f ? e : 0.2f * e;
        exw[w][lane * 8 + h] = exp2f(e * 1.44269504f) * rden[h];
      }
    }
    __asm__ __volatile__("s_waitcnt lgkmcnt(0)" ::: "memory");
    for (int j = 0; j < nn; j++) {
      int s = sarr[w][j];
      s16x8 hv = *(const s16x8*)(hs + (size_t)s * 512 + lane * 8);   // all 8 heads, feature=lane
      float4 e0 = *(const float4*)&exw[w][j * 8];
      float4 e1 = *(const float4*)&exw[w][j * 8 + 4];
      acc8[0] += e0.x * b2f((u16)hv[0]);
      acc8[1] += e0.y * b2f((u16)hv[1]);
      acc8[2] += e0.z * b2f((u16)hv[2]);
      acc8[3] += e0.w * b2f((u16)hv[3]);
      acc8[4] += e1.x * b2f((u16)hv[4]);
      acc8[5] += e1.y * b2f((u16)hv[5]);
      acc8[6] += e1.z * b2f((u16)hv[6]);
      acc8[7] += e1.w * b2f((u16)hv[7]);
    }
  }
  float acc = ((acc8[0] + acc8[1]) + (acc8[2] + acc8[3])) + ((acc8[4] + acc8[5]) + (acc8[6] + acc8[7]));
  acc *= scale;
  sacc[w][lane] = acc;
  __syncthreads();
  if (half == 0) {
    float tot = sacc[w][lane] + sacc[w + 1][lane];
    if (accum) out[dst * 64 + lane] += tot;
    else out[dst * 64 + lane] = tot;
  }
}

extern "C" void kernel_launch(void* const* d_in, const int* in_sizes, int n_in,
                              void* d_out, int out_size, void* d_ws, size_t ws_size,
                              hipStream_t stream) {
  const float* xu = (const float*)d_in[0];
  const float* xi = (const float*)d_in[1];
  const float* Wv = (const float*)d_in[2];
  const float* bv = (const float*)d_in[3];
  const float* Wq = (const float*)d_in[4];
  const float* bq = (const float*)d_in[5];
  const float* Wk = (const float*)d_in[6];
  const float* bk = (const float*)d_in[7];
  const int* src1 = (const int*)d_in[8];
  const int* dst1 = (const int*)d_in[9];
  const int* src2 = (const int*)d_in[10];
  const int* dst2 = (const int*)d_in[11];
  const int* src3 = (const int*)d_in[12];
  const int* dst3 = (const int*)d_in[13];
  float* out_user = (float*)d_out;
  float* out_item = out_user + (size_t)NND * 64;

  char* w = (char*)d_ws;
  auto alloc = [&](size_t sz) -> char* {
    char* p = w; w += (sz + 255) & ~(size_t)255; return p;
  };
  // total ~83 MB
  u16* H    = (u16*)alloc((size_t)NND * 512 * 2);          // 51.2 MB shared h table
  u16* WT   = (u16*)alloc((size_t)3 * 512 * 256 * 2);      // 0.8 MB
  float* FW = (float*)alloc((size_t)3 * 16 * 256 * 4);     // 49 KB fused qk weights
  float* FB = (float*)alloc((size_t)3 * 16 * 4);
  float* Q0 = (float*)alloc((size_t)NND * 8 * 4);
  float* K0 = (float*)alloc((size_t)NND * 8 * 4);
  float* Q1 = (float*)alloc((size_t)NND * 8 * 4);
  float* K1 = (float*)alloc((size_t)NND * 8 * 4);
  float* Q2 = (float*)alloc((size_t)NND * 8 * 4);
  float* K2 = (float*)alloc((size_t)NND * 8 * 4);          // 9.6 MB total q/k
  int* ROWPTR = (int*)alloc(((size_t)3 * NND + 1) * 4);
  int* BC   = (int*)alloc(TOTB * 4);
  int* BB   = (int*)alloc(TOTB * 4);
  int* BCUR = (int*)alloc(TOTB * 4);
  int* CSRC = (int*)alloc((size_t)3 * EDG * 4);            // 19.2 MB
  unsigned* PAIRS = (unsigned*)H;                          // aliased: dead before H written
  (void)ws_size; (void)n_in; (void)in_sizes; (void)out_size;

  // --- CSR build (bucket partition, cheap grouping) ---
  k_zero<<<(TOTB + 255) / 256, 256, 0, stream>>>(BC, TOTB);
  kb_count<<<dim3(256, 3), 256, 0, stream>>>(dst1, dst2, dst3, BC);
  kb_scan<<<1, 1024, 0, stream>>>(BC, BB, BCUR, ROWPTR);
  kb_scatter<<<dim3((EDG + TS - 1) / TS, 3), 256, 0, stream>>>(src1, dst1, src2, dst2, src3, dst3, BCUR, PAIRS);
  kb_build<<<dim3(NBK, 3), 256, 0, stream>>>(PAIRS, BB, BC, ROWPTR, CSRC);

  // --- weight prep ---
  k_prepw<<<(3 * 512 * 256 + 255) / 256, 256, 0, stream>>>(Wv, WT);
  k_fusew<<<48, 256, 0, stream>>>(Wv, bv, Wq, bq, Wk, bk, FW, FB);

  // --- q/k logits (2 fused passes) ---
  k_qk_u<<<1024, 256, 0, stream>>>(xu, FW, FB, K0, Q1, Q2, K2, NND);
  k_qk_i<<<1024, 256, 0, stream>>>(xi, FW, FB, Q0, K1, NND);

  // --- per relation: GEMM into shared H, then edge aggregation ---
  dim3 gg((NND + 127) / 128, 4);
  k_gemm<<<gg, 256, 0, stream>>>(xu, WT,                 bv,        H, NND);
  k_edge<<<NND / 2, 256, 0, stream>>>(ROWPTR,           CSRC, Q0, K0, H, out_item, 0.125f,  0);
  k_gemm<<<gg, 256, 0, stream>>>(xi, WT + 512 * 256,     bv + 512,  H, NND);
  k_edge<<<NND / 2, 256, 0, stream>>>(ROWPTR + NND,     CSRC, Q1, K1, H, out_user, 0.0625f, 0);
  k_gemm<<<gg, 256, 0, stream>>>(xu, WT + 2 * 512 * 256, bv + 1024, H, NND);
  k_edge<<<NND / 2, 256, 0, stream>>>(ROWPTR + 2 * NND, CSRC, Q2, K2, H, out_user, 0.0625f, 1);
}